// Round 1
// 578.251 us; speedup vs baseline: 1.0008x; 1.0008x over previous
//
#include <hip/hip_runtime.h>

#define EPS_F 0.1f
#define SCAN_THREADS 1024
#define SCAN_ITEMS 12  // N / SCAN_THREADS = 12288 / 1024

// Fused kernel: compute center/err/cond, block-wide inclusive scan for row
// assignment, write row 0 (center) and scatter err values. Runs AFTER the
// memset in stream order. Single block, 1024 threads, 12 elements/thread.
__global__ __launch_bounds__(SCAN_THREADS) void finalize_kernel(
    const float* __restrict__ x,
    float* __restrict__ out,
    int N)
{
    __shared__ int wave_sums[16];  // 1024 / 64 = 16 waves

    const int t    = threadIdx.x;
    const int lane = t & 63;
    const int wave = t >> 6;
    const int base = t * SCAN_ITEMS;

    float c_[SCAN_ITEMS], e_[SCAN_ITEMS];
    int   cnd[SCAN_ITEMS];

    int local = 0;
    #pragma unroll
    for (int i = 0; i < SCAN_ITEMS; i++) {
        float xv = x[base + i];
        float lo = fmaxf(EPS_F - xv, 0.0f) * 0.5f;
        float hi = fmaxf(xv - (1.0f - EPS_F), 0.0f) * 0.5f;
        c_[i] = xv + lo - hi;
        float ev = EPS_F - lo - hi;
        e_[i] = ev;
        cnd[i] = (ev >= 0.0f) ? 1 : 0;
        local += cnd[i];
    }

    // Wave-level inclusive scan of per-thread counts (width 64).
    int inc = local;
    #pragma unroll
    for (int off = 1; off < 64; off <<= 1) {
        int y = __shfl_up(inc, off, 64);
        if (lane >= off) inc += y;
    }
    if (lane == 63) wave_sums[wave] = inc;
    __syncthreads();

    // Serial scan over the 16 wave totals (trivial cost).
    if (t == 0) {
        int acc = 0;
        #pragma unroll
        for (int w = 0; w < 16; w++) {
            acc += wave_sums[w];
            wave_sums[w] = acc;  // inclusive
        }
    }
    __syncthreads();

    const int wave_off = (wave == 0) ? 0 : wave_sums[wave - 1];
    int run = wave_off + (inc - local);  // exclusive prefix for this thread

    #pragma unroll
    for (int i = 0; i < SCAN_ITEMS; i++) {
        const int k = base + i;
        out[k] = c_[i];  // row 0, coalesced across the block
        run += cnd[i];
        if (cnd[i]) {
            // selected element k -> row `run` (1-based inclusive cumsum)
            out[(size_t)run * (size_t)N + (size_t)k] = e_[i];
        }
    }
}

extern "C" void kernel_launch(void* const* d_in, const int* in_sizes, int n_in,
                              void* d_out, int out_size, void* d_ws, size_t ws_size,
                              hipStream_t stream)
{
    const float* x = (const float*)d_in[0];
    float* out = (float*)d_out;
    const int N = in_sizes[0];  // 12288

    // 1) zero-fill EXACTLY the logical output: (1+N) rows x N cols of f32.
    //    Previous version used out_size*sizeof(float), which rocprof showed
    //    writing 2,416,115,712 bytes (WRITE_SIZE 2,359,488 KB) = 4.00x the
    //    604,028,928-byte output -> out_size was already in bytes. Computing
    //    the byte count from N is correct under either unit convention.
    const size_t out_bytes = (size_t)(N + 1) * (size_t)N * sizeof(float);
    hipMemsetAsync(d_out, 0, out_bytes, stream);

    // 2) fused scan + row-0 + scatter (stream order guarantees fill is done)
    finalize_kernel<<<1, SCAN_THREADS, 0, stream>>>(x, out, N);
}